// Round 6
// baseline (3436.924 us; speedup 1.0000x reference)
//
#include <hip/hip_runtime.h>
#include <hip/hip_bf16.h>
#include <math.h>

#define SCALE_ 0.17677669529663687f

// rope[t][j] = (cos, sin) of t * 10000^(-j/16), computed in double.
__global__ __launch_bounds__(256) void d_rope(float* __restrict__ rope) {
  int i = blockIdx.x * 256 + threadIdx.x;  // 8192 = 512*16
  int t = i >> 4, j = i & 15;
  double inv = pow(10000.0, -(double)j / 16.0);
  double ang = (double)t * inv;
  rope[2 * i]     = (float)cos(ang);
  rope[2 * i + 1] = (float)sin(ang);
}

// pm[ball][c] = mean over 512 tokens of pos
__global__ __launch_bounds__(64) void d_pm(const float* __restrict__ pos,
                                           float* __restrict__ pm) {
  int i = threadIdx.x;
  if (i >= 48) return;
  int ball = i / 3, c = i % 3;
  float s = 0.f;
  for (int t = 0; t < 512; ++t) s += pos[(size_t)(ball * 512 + t) * 3 + c];
  pm[i] = s * (1.f / 512.f);
}

// hn[tok][d] = RMSNorm(x + rel@Wpe + bpe) * rms_w   (one thread per token)
__global__ __launch_bounds__(256) void d_hn(const float* __restrict__ x,
                                            const float* __restrict__ pos,
                                            const float* __restrict__ pm,
                                            const float* __restrict__ Wpe,
                                            const float* __restrict__ bpe,
                                            const float* __restrict__ rmsw,
                                            float* __restrict__ hn) {
  int tok = blockIdx.x * 256 + threadIdx.x;  // 8192
  int ball = tok >> 9;
  float r0 = pos[tok * 3 + 0] - pm[ball * 3 + 0];
  float r1 = pos[tok * 3 + 1] - pm[ball * 3 + 1];
  float r2 = pos[tok * 3 + 2] - pm[ball * 3 + 2];
  const float* xr = x + (size_t)tok * 256;
  float ss = 0.f;
  for (int d = 0; d < 256; ++d) {
    float hx = xr[d] + r0 * Wpe[d] + r1 * Wpe[256 + d] + r2 * Wpe[512 + d] + bpe[d];
    ss += hx * hx;
  }
  float inv = 1.f / sqrtf(ss * (1.f / 256.f) + 1e-6f);
  float* hr = hn + (size_t)tok * 256;
  for (int d = 0; d < 256; ++d) {
    float hx = xr[d] + r0 * Wpe[d] + r1 * Wpe[256 + d] + r2 * Wpe[512 + d] + bpe[d];
    hr[d] = hx * inv * rmsw[d];
  }
}

// qkv: one thread per (token, col) of the 768-wide product; scatter head-major.
__global__ __launch_bounds__(256) void d_qkv(const float* __restrict__ hn,
                                             const float* __restrict__ Wqkv,
                                             float* __restrict__ q,
                                             float* __restrict__ k,
                                             float* __restrict__ v) {
  size_t gid = (size_t)blockIdx.x * 256 + threadIdx.x;  // 8192*768
  int tok = (int)(gid / 768), col = (int)(gid % 768);
  const float* hr = hn + (size_t)tok * 256;
  float s = 0.f;
  for (int d = 0; d < 256; ++d) s += hr[d] * Wqkv[(size_t)d * 768 + col];
  int which = col >> 8, cj = col & 255;
  int h = cj >> 5, dd = cj & 31;
  int ball = tok >> 9, t = tok & 511;
  float* dst = which == 0 ? q : which == 1 ? k : v;
  dst[((size_t)(ball * 8 + h) * 512 + t) * 32 + dd] = s;
}

// rotate: dst = rope(src), one thread per (nh, t, pair)
__global__ __launch_bounds__(256) void d_rot(const float* __restrict__ src,
                                             const float* __restrict__ rope,
                                             float* __restrict__ dst) {
  int gid = blockIdx.x * 256 + threadIdx.x;  // 128*512*16 = 1,048,576
  int p = gid & 15;
  int t = (gid >> 4) & 511;
  int nh = gid >> 13;
  float c = rope[(t * 16 + p) * 2], s = rope[(t * 16 + p) * 2 + 1];
  const float* sp = src + ((size_t)nh * 512 + t) * 32;
  float x1 = sp[2 * p], x2 = sp[2 * p + 1];
  float* dp = dst + ((size_t)nh * 512 + t) * 32;
  dp[2 * p]     = x1 * c - x2 * s;
  dp[2 * p + 1] = x1 * s + x2 * c;
}

// gates = sigmoid(hn @ Wg), one thread per (token, j)
__global__ __launch_bounds__(256) void d_gates(const float* __restrict__ hn,
                                               const float* __restrict__ Wg,
                                               float* __restrict__ gates) {
  int gid = blockIdx.x * 256 + threadIdx.x;  // 196608
  int tok = gid / 24, j = gid % 24;
  const float* hr = hn + (size_t)tok * 256;
  float s = 0.f;
  for (int d = 0; d < 256; ++d) s += hr[d] * Wg[d * 24 + j];
  gates[gid] = 1.f / (1.f + expf(-s));
}

// gMLP hidden: hh[h][row][o] = relu(sum_i (kv_gather + posw)[i] * w1[h][i][o])
__global__ __launch_bounds__(256) void d_g1(const float* __restrict__ kv,
                                            const float* __restrict__ posw,
                                            const float* __restrict__ w1,
                                            float* __restrict__ hh) {
  size_t gid = (size_t)blockIdx.x * 256 + threadIdx.x;  // 8*496*1024
  int o = (int)(gid & 1023);
  int rem = (int)(gid >> 10);          // h*496 + row
  int h = rem / 496, row = rem % 496;
  int nb = row / 31, bb = row % 31;
  const float* w1p = w1 + (size_t)h * 1048576 + o;
  const float* kvb = kv + ((size_t)(nb * 8 + h) * 512 + bb * 16) * 32;
  const float* pw = posw + (size_t)h * 1024;
  float s = 0.f;
  for (int i = 0; i < 1024; ++i) {
    float a = kvb[i] + pw[i];
    s += a * w1p[(size_t)i * 1024];
  }
  hh[gid] = fmaxf(s, 0.f);
}

// gMLP out: ck[(nb*8+h)][bb][o] = sum_i hh[h][row][i] * w2[h][i][o]
__global__ __launch_bounds__(256) void d_g2(const float* __restrict__ hh,
                                            const float* __restrict__ w2,
                                            float* __restrict__ outp) {
  int gid = blockIdx.x * 256 + threadIdx.x;  // 8*496*32 = 126976
  int o = gid & 31;
  int rem = gid >> 5;                  // h*496 + row
  int h = rem / 496, row = rem % 496;
  int nb = row / 31, bb = row % 31;
  const float* hr = hh + (size_t)rem * 1024;
  const float* w2p = w2 + (size_t)h * 32768 + o;
  float s = 0.f;
  for (int i = 0; i < 1024; ++i) s += hr[i] * w2p[(size_t)i * 32];
  outp[((size_t)(nb * 8 + h) * 31 + bb) * 32 + o] = s;
}

// compressed attention, one thread per (nh, t): writes obuf = g0*c_out, emits sel
__global__ __launch_bounds__(256) void d_cattn(const float* __restrict__ q,
                                               const float* __restrict__ ck,
                                               const float* __restrict__ cv,
                                               const float* __restrict__ mem_ck,
                                               const float* __restrict__ mem_cv,
                                               const float* __restrict__ gates,
                                               float* __restrict__ obuf,
                                               int* __restrict__ sel) {
  int gid = blockIdx.x * 256 + threadIdx.x;  // 65536
  int nh = gid >> 9, t = gid & 511;
  int h = nh & 7, ball = nh >> 3;
  const float* qp = q + (size_t)gid * 32;
  float sc[32];
  float mx = -INFINITY;
#pragma unroll
  for (int j = 0; j < 32; ++j) {
    float s = -INFINITY;
    bool valid = (j == 0) || (t >= (j - 1) * 16 + 31);
    if (valid) {
      const float* kp = (j == 0) ? (mem_ck + h * 32)
                                 : (ck + ((size_t)nh * 31 + (j - 1)) * 32);
      s = 0.f;
      for (int d = 0; d < 32; ++d) s += qp[d] * kp[d];
      s *= SCALE_;
    }
    sc[j] = s;
    mx = fmaxf(mx, s);
  }
  float e[32];
  float den = 0.f;
#pragma unroll
  for (int j = 0; j < 32; ++j) { e[j] = expf(sc[j] - mx); den += e[j]; }
  float num[32];
#pragma unroll
  for (int d = 0; d < 32; ++d) num[d] = 0.f;
#pragma unroll
  for (int j = 0; j < 32; ++j) {
    const float* vp = (j == 0) ? (mem_cv + h * 32)
                               : (cv + ((size_t)nh * 31 + (j - 1)) * 32);
    float p = e[j];
    for (int d = 0; d < 32; ++d) num[d] += p * vp[d];
  }
  float inv = 1.f / den;
  float g0 = gates[(size_t)(ball * 512 + t) * 24 + h * 3];
  float* op = obuf + (size_t)(ball * 512 + t) * 256 + h * 32;
  for (int d = 0; d < 32; ++d) op[d] = num[d] * inv * g0;

  // block importance + argmax (literal OVERLAP); scale-invariant so e[] unnormalized ok
  int s_idx = 0;
  if (t >= 32) {
    int fn = t >> 5;
    float best = -INFINITY;
    for (int f = 0; f < fn; ++f) {
      float im = 0.f;
#pragma unroll
      for (int j = 0; j < 31; ++j) {
        int a = j * 16, b2 = a + 32, fa = f * 32, fb = fa + 32;
        int lo = a > fa ? a : fa;
        int hi = b2 < fb ? b2 : fb;
        if (hi > lo) im += e[j + 1] * (float)(hi - lo) * (1.f / 32.f);
      }
      if (im > best) { best = im; s_idx = f; }
    }
  }
  sel[gid] = s_idx;
}

// fine attention, one thread per (nh, t): obuf += g1 * f_out
__global__ __launch_bounds__(256) void d_fattn(const float* __restrict__ rq,
                                               const float* __restrict__ rk,
                                               const float* __restrict__ v,
                                               const int* __restrict__ sel,
                                               const float* __restrict__ gates,
                                               float* __restrict__ obuf) {
  int gid = blockIdx.x * 256 + threadIdx.x;  // 65536
  int nh = gid >> 9, t = gid & 511;
  int h = nh & 7, ball = nh >> 3;
  int f0 = t >> 5, qi = t & 31;
  int sb = sel[gid];
  bool hs = (t >= 32);
  const float* qp = rq + (size_t)gid * 32;
  float so[32], ss[32];
  float mx = -INFINITY;
#pragma unroll
  for (int j = 0; j < 32; ++j) {
    float s = -INFINITY;
    if (qi >= j) {
      const float* kp = rk + ((size_t)nh * 512 + f0 * 32 + j) * 32;
      s = 0.f;
      for (int d = 0; d < 32; ++d) s += qp[d] * kp[d];
      s *= SCALE_;
    }
    so[j] = s;
    mx = fmaxf(mx, s);
  }
#pragma unroll
  for (int j = 0; j < 32; ++j) {
    float s = -INFINITY;
    if (hs) {
      const float* kp = rk + ((size_t)nh * 512 + sb * 32 + j) * 32;
      s = 0.f;
      for (int d = 0; d < 32; ++d) s += qp[d] * kp[d];
      s *= SCALE_;
    }
    ss[j] = s;
    mx = fmaxf(mx, s);
  }
  float den = 0.f;
  float num[32];
#pragma unroll
  for (int d = 0; d < 32; ++d) num[d] = 0.f;
#pragma unroll
  for (int j = 0; j < 32; ++j) {
    float p = expf(so[j] - mx);
    den += p;
    const float* vp = v + ((size_t)nh * 512 + f0 * 32 + j) * 32;
    for (int d = 0; d < 32; ++d) num[d] += p * vp[d];
  }
#pragma unroll
  for (int j = 0; j < 32; ++j) {
    float p = expf(ss[j] - mx);
    den += p;
    const float* vp = v + ((size_t)nh * 512 + sb * 32 + j) * 32;
    for (int d = 0; d < 32; ++d) num[d] += p * vp[d];
  }
  float inv = 1.f / den;
  float g1 = gates[(size_t)(ball * 512 + t) * 24 + h * 3 + 1];
  float* op = obuf + (size_t)(ball * 512 + t) * 256 + h * 32;
  for (int d = 0; d < 32; ++d) op[d] += num[d] * inv * g1;
}

// sliding-window attention, one thread per (nh, t): obuf += g2 * sw_out
__global__ __launch_bounds__(256) void d_swattn(const float* __restrict__ rq,
                                                const float* __restrict__ rk,
                                                const float* __restrict__ v,
                                                const float* __restrict__ gates,
                                                float* __restrict__ obuf) {
  int gid = blockIdx.x * 256 + threadIdx.x;  // 65536
  int nh = gid >> 9, t = gid & 511;
  int h = nh & 7, ball = nh >> 3;
  int b = t >> 5, qi = t & 31;
  const float* qp = rq + (size_t)gid * 32;
  float sc[64];
  float mx = -INFINITY;
#pragma unroll
  for (int kk = 0; kk < 64; ++kk) {
    bool valid = (kk > qi) && (kk <= qi + 32) && ((b > 0) || (kk >= 32));
    float s = -INFINITY;
    if (valid) {
      int tk = (kk < 32) ? ((b - 1) * 32 + kk) : (b * 32 + kk - 32);
      const float* kp = rk + ((size_t)nh * 512 + tk) * 32;
      s = 0.f;
      for (int d = 0; d < 32; ++d) s += qp[d] * kp[d];
      s *= SCALE_;
    }
    sc[kk] = s;
    mx = fmaxf(mx, s);
  }
  float den = 0.f;
  float num[32];
#pragma unroll
  for (int d = 0; d < 32; ++d) num[d] = 0.f;
#pragma unroll
  for (int kk = 0; kk < 64; ++kk) {
    bool valid = (kk > qi) && (kk <= qi + 32) && ((b > 0) || (kk >= 32));
    if (valid) {
      float p = expf(sc[kk] - mx);
      den += p;
      int tk = (kk < 32) ? ((b - 1) * 32 + kk) : (b * 32 + kk - 32);
      const float* vp = v + ((size_t)nh * 512 + tk) * 32;
      for (int d = 0; d < 32; ++d) num[d] += p * vp[d];
    }
  }
  float inv = 1.f / den;
  float g2 = gates[(size_t)(ball * 512 + t) * 24 + h * 3 + 2];
  float* op = obuf + (size_t)(ball * 512 + t) * 256 + h * 32;
  for (int d = 0; d < 32; ++d) op[d] += num[d] * inv * g2;
}

// final projection, one thread per (token, col), f32 store (reference output dtype)
__global__ __launch_bounds__(256) void d_proj(const float* __restrict__ obuf,
                                              const float* __restrict__ Wo,
                                              float* __restrict__ outp) {
  int gid = blockIdx.x * 256 + threadIdx.x;  // 2,097,152
  int tok = gid >> 8, col = gid & 255;
  const float* orow = obuf + (size_t)tok * 256;
  float s = 0.f;
  for (int c = 0; c < 256; ++c) s += orow[c] * Wo[c * 256 + col];
  outp[gid] = s;
}

extern "C" void kernel_launch(void* const* d_in, const int* in_sizes, int n_in,
                              void* d_out, int out_size, void* d_ws, size_t ws_size,
                              hipStream_t stream) {
  const float* x      = (const float*)d_in[0];
  const float* pos    = (const float*)d_in[1];
  const float* Wpe    = (const float*)d_in[2];
  const float* bpe    = (const float*)d_in[3];
  const float* rms_w  = (const float*)d_in[4];
  const float* Wqkv   = (const float*)d_in[5];
  const float* kpos   = (const float*)d_in[6];
  const float* vpos   = (const float*)d_in[7];
  const float* kw1    = (const float*)d_in[8];
  const float* kw2    = (const float*)d_in[9];
  const float* vw1    = (const float*)d_in[10];
  const float* vw2    = (const float*)d_in[11];
  const float* mem_ck = (const float*)d_in[12];
  const float* mem_cv = (const float*)d_in[13];
  const float* Wg     = (const float*)d_in[14];
  const float* Wo     = (const float*)d_in[15];
  float* out = (float*)d_out;

  float* ws = (float*)d_ws;
  const size_t TOK = 2097152;  // 8192*256
  float* hn    = ws;                 // 2,097,152
  float* q     = ws + TOK;           // 2,097,152
  float* k     = ws + 2 * TOK;
  float* v     = ws + 3 * TOK;
  float* rq    = ws + 4 * TOK;
  float* rk    = ws + 5 * TOK;
  float* obuf  = ws + 6 * TOK;
  float* hh    = ws + 7 * TOK;       // 4,063,232
  float* ck    = hh + 4063232;       // 126,976
  float* cv    = ck + 126976;        // 126,976
  float* gates = cv + 126976;        // 196,608
  float* rope  = gates + 196608;     // 16,384
  float* pm    = rope + 16384;       // 64
  int*   sel   = (int*)(pm + 64);    // 65,536
  // total ~ 19.3M floats ~ 77 MB

  d_rope<<<32, 256, 0, stream>>>(rope);
  d_pm<<<1, 64, 0, stream>>>(pos, pm);
  d_hn<<<32, 256, 0, stream>>>(x, pos, pm, Wpe, bpe, rms_w, hn);
  d_qkv<<<24576, 256, 0, stream>>>(hn, Wqkv, q, k, v);
  d_rot<<<4096, 256, 0, stream>>>(q, rope, rq);
  d_rot<<<4096, 256, 0, stream>>>(k, rope, rk);
  d_gates<<<768, 256, 0, stream>>>(hn, Wg, gates);
  d_g1<<<15872, 256, 0, stream>>>(k, kpos, kw1, hh);
  d_g2<<<496, 256, 0, stream>>>(hh, kw2, ck);
  d_g1<<<15872, 256, 0, stream>>>(v, vpos, vw1, hh);
  d_g2<<<496, 256, 0, stream>>>(hh, vw2, cv);
  d_cattn<<<256, 256, 0, stream>>>(q, ck, cv, mem_ck, mem_cv, gates, obuf, sel);
  d_fattn<<<256, 256, 0, stream>>>(rq, rk, v, sel, gates, obuf);
  d_swattn<<<256, 256, 0, stream>>>(rq, rk, v, gates, obuf);
  d_proj<<<8192, 256, 0, stream>>>(obuf, Wo, out);
}

// Round 7
// 924.151 us; speedup vs baseline: 3.7190x; 3.7190x over previous
//
#include <hip/hip_runtime.h>
#include <hip/hip_bf16.h>
#include <math.h>

#define SCALE_ 0.17677669529663687f

// rope[t][j] = (cos, sin) of t * 10000^(-j/16), computed in double.
__global__ __launch_bounds__(256) void d_rope(float* __restrict__ rope) {
  int i = blockIdx.x * 256 + threadIdx.x;  // 8192 = 512*16
  int t = i >> 4, j = i & 15;
  double inv = pow(10000.0, -(double)j / 16.0);
  double ang = (double)t * inv;
  rope[2 * i]     = (float)cos(ang);
  rope[2 * i + 1] = (float)sin(ang);
}

// pm[ball][c] = mean over 512 tokens of pos
__global__ __launch_bounds__(64) void d_pm(const float* __restrict__ pos,
                                           float* __restrict__ pm) {
  int i = threadIdx.x;
  if (i >= 48) return;
  int ball = i / 3, c = i % 3;
  float s = 0.f;
  for (int t = 0; t < 512; ++t) s += pos[(size_t)(ball * 512 + t) * 3 + c];
  pm[i] = s * (1.f / 512.f);
}

// hn[tok][d] = RMSNorm(x + rel@Wpe + bpe) * rms_w   (one thread per token)
__global__ __launch_bounds__(256) void d_hn(const float* __restrict__ x,
                                            const float* __restrict__ pos,
                                            const float* __restrict__ pm,
                                            const float* __restrict__ Wpe,
                                            const float* __restrict__ bpe,
                                            const float* __restrict__ rmsw,
                                            float* __restrict__ hn) {
  int tok = blockIdx.x * 256 + threadIdx.x;  // 8192
  int ball = tok >> 9;
  float r0 = pos[tok * 3 + 0] - pm[ball * 3 + 0];
  float r1 = pos[tok * 3 + 1] - pm[ball * 3 + 1];
  float r2 = pos[tok * 3 + 2] - pm[ball * 3 + 2];
  const float* xr = x + (size_t)tok * 256;
  float ss = 0.f;
  for (int d = 0; d < 256; ++d) {
    float hx = xr[d] + r0 * Wpe[d] + r1 * Wpe[256 + d] + r2 * Wpe[512 + d] + bpe[d];
    ss += hx * hx;
  }
  float inv = 1.f / sqrtf(ss * (1.f / 256.f) + 1e-6f);
  float* hr = hn + (size_t)tok * 256;
  for (int d = 0; d < 256; ++d) {
    float hx = xr[d] + r0 * Wpe[d] + r1 * Wpe[256 + d] + r2 * Wpe[512 + d] + bpe[d];
    hr[d] = hx * inv * rmsw[d];
  }
}

// qkv = hn @ Wqkv, tiled 64x64, scatter q/k/v head-major
__global__ __launch_bounds__(256) void k_qkv(const float* __restrict__ A,
                                             const float* __restrict__ B,
                                             float* __restrict__ qo,
                                             float* __restrict__ ko,
                                             float* __restrict__ vo) {
  __shared__ float As[32][64];
  __shared__ float Bs[32][64];
  const int m0 = blockIdx.x * 64;
  const int n0 = blockIdx.y * 64;
  const int tid = threadIdx.x;
  const int tx = tid & 15, ty = tid >> 4;
  float acc[4][4] = {};
  for (int k0 = 0; k0 < 256; k0 += 32) {
#pragma unroll
    for (int i = 0; i < 8; ++i) {
      int li = tid + i * 256;
      int r = li >> 5, c = li & 31;
      As[c][r] = A[(size_t)(m0 + r) * 256 + k0 + c];
    }
#pragma unroll
    for (int i = 0; i < 8; ++i) {
      int li = tid + i * 256;
      int r = li >> 6, c = li & 63;
      Bs[r][c] = B[(size_t)(k0 + r) * 768 + n0 + c];
    }
    __syncthreads();
#pragma unroll
    for (int kk = 0; kk < 32; ++kk) {
      float a[4], b[4];
#pragma unroll
      for (int i = 0; i < 4; ++i) a[i] = As[kk][ty * 4 + i];
#pragma unroll
      for (int j = 0; j < 4; ++j) b[j] = Bs[kk][tx * 4 + j];
#pragma unroll
      for (int i = 0; i < 4; ++i)
#pragma unroll
        for (int j = 0; j < 4; ++j) acc[i][j] += a[i] * b[j];
    }
    __syncthreads();
  }
#pragma unroll
  for (int i = 0; i < 4; ++i) {
    int row = m0 + ty * 4 + i;
    int nb = row >> 9, t = row & 511;
#pragma unroll
    for (int j = 0; j < 4; ++j) {
      int col = n0 + tx * 4 + j;
      int which = col >> 8, cj = col & 255;
      int h = cj >> 5, d = cj & 31;
      float* dst = which == 0 ? qo : which == 1 ? ko : vo;
      dst[((size_t)(nb * 8 + h) * 512 + t) * 32 + d] = acc[i][j];
    }
  }
}

// rotate: dst = rope(src), one thread per (nh, t, pair)
__global__ __launch_bounds__(256) void d_rot(const float* __restrict__ src,
                                             const float* __restrict__ rope,
                                             float* __restrict__ dst) {
  int gid = blockIdx.x * 256 + threadIdx.x;  // 1,048,576
  int p = gid & 15;
  int t = (gid >> 4) & 511;
  int nh = gid >> 13;
  float c = rope[(t * 16 + p) * 2], s = rope[(t * 16 + p) * 2 + 1];
  const float* sp = src + ((size_t)nh * 512 + t) * 32;
  float x1 = sp[2 * p], x2 = sp[2 * p + 1];
  float* dp = dst + ((size_t)nh * 512 + t) * 32;
  dp[2 * p]     = x1 * c - x2 * s;
  dp[2 * p + 1] = x1 * s + x2 * c;
}

// gates = sigmoid(hn @ Wg), one thread per (token, j)
__global__ __launch_bounds__(256) void d_gates(const float* __restrict__ hn,
                                               const float* __restrict__ Wg,
                                               float* __restrict__ gates) {
  int gid = blockIdx.x * 256 + threadIdx.x;  // 196608
  int tok = gid / 24, j = gid % 24;
  const float* hr = hn + (size_t)tok * 256;
  float s = 0.f;
  for (int d = 0; d < 256; ++d) s += hr[d] * Wg[d * 24 + j];
  gates[gid] = 1.f / (1.f + expf(-s));
}

// gMLP layer 1 tiled: hh[h][row][o] = relu((gather(kv)+posw) @ w1[h]), 64x64 tiles
__global__ __launch_bounds__(256) void k_gmlp1(const float* __restrict__ kv,
                                               const float* __restrict__ posw,
                                               const float* __restrict__ w1,
                                               float* __restrict__ hb) {
  __shared__ float As[32][64];
  __shared__ float Bs[32][64];
  const int h = blockIdx.z;
  const int m0 = blockIdx.x * 64;
  const int n0 = blockIdx.y * 64;
  const int tid = threadIdx.x;
  const int tx = tid & 15, ty = tid >> 4;
  float acc[4][4] = {};
  for (int k0 = 0; k0 < 1024; k0 += 32) {
#pragma unroll
    for (int i = 0; i < 8; ++i) {
      int li = tid + i * 256;
      int r = li >> 5, c = li & 31;
      int row = m0 + r;
      float vv = 0.f;
      if (row < 496) {
        int nb = row / 31, bb = row % 31;
        int ii = k0 + c;
        int cc = ii >> 5, d = ii & 31;
        vv = kv[((size_t)(nb * 8 + h) * 512 + bb * 16 + cc) * 32 + d] + posw[(h * 32 + cc) * 32 + d];
      }
      As[c][r] = vv;
    }
#pragma unroll
    for (int i = 0; i < 8; ++i) {
      int li = tid + i * 256;
      int r = li >> 6, c = li & 63;
      Bs[r][c] = w1[(size_t)h * 1048576 + (size_t)(k0 + r) * 1024 + n0 + c];
    }
    __syncthreads();
#pragma unroll
    for (int kk = 0; kk < 32; ++kk) {
      float a[4], b[4];
#pragma unroll
      for (int i = 0; i < 4; ++i) a[i] = As[kk][ty * 4 + i];
#pragma unroll
      for (int j = 0; j < 4; ++j) b[j] = Bs[kk][tx * 4 + j];
#pragma unroll
      for (int i = 0; i < 4; ++i)
#pragma unroll
        for (int j = 0; j < 4; ++j) acc[i][j] += a[i] * b[j];
    }
    __syncthreads();
  }
#pragma unroll
  for (int i = 0; i < 4; ++i) {
    int row = m0 + ty * 4 + i;
    if (row < 496) {
#pragma unroll
      for (int j = 0; j < 4; ++j)
        hb[((size_t)h * 496 + row) * 1024 + n0 + tx * 4 + j] = fmaxf(acc[i][j], 0.f);
    }
  }
}

// gMLP out: ck[(nb*8+h)][bb][o] = sum_i hh[h][row][i] * w2[h][i][o]
__global__ __launch_bounds__(256) void d_g2(const float* __restrict__ hh,
                                            const float* __restrict__ w2,
                                            float* __restrict__ outp) {
  int gid = blockIdx.x * 256 + threadIdx.x;  // 126976
  int o = gid & 31;
  int rem = gid >> 5;                  // h*496 + row
  int h = rem / 496, row = rem % 496;
  int nb = row / 31, bb = row % 31;
  const float* hr = hh + (size_t)rem * 1024;
  const float* w2p = w2 + (size_t)h * 32768 + o;
  float s = 0.f;
  for (int i = 0; i < 1024; ++i) s += hr[i] * w2p[(size_t)i * 32];
  outp[((size_t)(nb * 8 + h) * 31 + bb) * 32 + o] = s;
}

// compressed attention, one thread per (nh, t): writes obuf = g0*c_out, emits sel
__global__ __launch_bounds__(256) void d_cattn(const float* __restrict__ q,
                                               const float* __restrict__ ck,
                                               const float* __restrict__ cv,
                                               const float* __restrict__ mem_ck,
                                               const float* __restrict__ mem_cv,
                                               const float* __restrict__ gates,
                                               float* __restrict__ obuf,
                                               int* __restrict__ sel) {
  int gid = blockIdx.x * 256 + threadIdx.x;  // 65536
  int nh = gid >> 9, t = gid & 511;
  int h = nh & 7, ball = nh >> 3;
  const float* qp = q + (size_t)gid * 32;
  float sc[32];
  float mx = -INFINITY;
#pragma unroll
  for (int j = 0; j < 32; ++j) {
    float s = -INFINITY;
    bool valid = (j == 0) || (t >= (j - 1) * 16 + 31);
    if (valid) {
      const float* kp = (j == 0) ? (mem_ck + h * 32)
                                 : (ck + ((size_t)nh * 31 + (j - 1)) * 32);
      s = 0.f;
      for (int d = 0; d < 32; ++d) s += qp[d] * kp[d];
      s *= SCALE_;
    }
    sc[j] = s;
    mx = fmaxf(mx, s);
  }
  float e[32];
  float den = 0.f;
#pragma unroll
  for (int j = 0; j < 32; ++j) { e[j] = expf(sc[j] - mx); den += e[j]; }
  float num[32];
#pragma unroll
  for (int d = 0; d < 32; ++d) num[d] = 0.f;
#pragma unroll
  for (int j = 0; j < 32; ++j) {
    const float* vp = (j == 0) ? (mem_cv + h * 32)
                               : (cv + ((size_t)nh * 31 + (j - 1)) * 32);
    float p = e[j];
    for (int d = 0; d < 32; ++d) num[d] += p * vp[d];
  }
  float inv = 1.f / den;
  float g0 = gates[(size_t)(ball * 512 + t) * 24 + h * 3];
  float* op = obuf + (size_t)(ball * 512 + t) * 256 + h * 32;
  for (int d = 0; d < 32; ++d) op[d] = num[d] * inv * g0;

  int s_idx = 0;
  if (t >= 32) {
    int fn = t >> 5;
    float best = -INFINITY;
    for (int f = 0; f < fn; ++f) {
      float im = 0.f;
#pragma unroll
      for (int j = 0; j < 31; ++j) {
        int a = j * 16, b2 = a + 32, fa = f * 32, fb = fa + 32;
        int lo = a > fa ? a : fa;
        int hi = b2 < fb ? b2 : fb;
        if (hi > lo) im += e[j + 1] * (float)(hi - lo) * (1.f / 32.f);
      }
      if (im > best) { best = im; s_idx = f; }
    }
  }
  sel[gid] = s_idx;
}

// fine attention, one thread per (nh, t): obuf += g1 * f_out
__global__ __launch_bounds__(256) void d_fattn(const float* __restrict__ rq,
                                               const float* __restrict__ rk,
                                               const float* __restrict__ v,
                                               const int* __restrict__ sel,
                                               const float* __restrict__ gates,
                                               float* __restrict__ obuf) {
  int gid = blockIdx.x * 256 + threadIdx.x;  // 65536
  int nh = gid >> 9, t = gid & 511;
  int h = nh & 7, ball = nh >> 3;
  int f0 = t >> 5, qi = t & 31;
  int sb = sel[gid];
  bool hs = (t >= 32);
  const float* qp = rq + (size_t)gid * 32;
  float so[32], ss[32];
  float mx = -INFINITY;
#pragma unroll
  for (int j = 0; j < 32; ++j) {
    float s = -INFINITY;
    if (qi >= j) {
      const float* kp = rk + ((size_t)nh * 512 + f0 * 32 + j) * 32;
      s = 0.f;
      for (int d = 0; d < 32; ++d) s += qp[d] * kp[d];
      s *= SCALE_;
    }
    so[j] = s;
    mx = fmaxf(mx, s);
  }
#pragma unroll
  for (int j = 0; j < 32; ++j) {
    float s = -INFINITY;
    if (hs) {
      const float* kp = rk + ((size_t)nh * 512 + sb * 32 + j) * 32;
      s = 0.f;
      for (int d = 0; d < 32; ++d) s += qp[d] * kp[d];
      s *= SCALE_;
    }
    ss[j] = s;
    mx = fmaxf(mx, s);
  }
  float den = 0.f;
  float num[32];
#pragma unroll
  for (int d = 0; d < 32; ++d) num[d] = 0.f;
#pragma unroll
  for (int j = 0; j < 32; ++j) {
    float p = expf(so[j] - mx);
    den += p;
    const float* vp = v + ((size_t)nh * 512 + f0 * 32 + j) * 32;
    for (int d = 0; d < 32; ++d) num[d] += p * vp[d];
  }
#pragma unroll
  for (int j = 0; j < 32; ++j) {
    float p = expf(ss[j] - mx);
    den += p;
    const float* vp = v + ((size_t)nh * 512 + sb * 32 + j) * 32;
    for (int d = 0; d < 32; ++d) num[d] += p * vp[d];
  }
  float inv = 1.f / den;
  float g1 = gates[(size_t)(ball * 512 + t) * 24 + h * 3 + 1];
  float* op = obuf + (size_t)(ball * 512 + t) * 256 + h * 32;
  for (int d = 0; d < 32; ++d) op[d] += num[d] * inv * g1;
}

// sliding-window attention, one thread per (nh, t): obuf += g2 * sw_out
__global__ __launch_bounds__(256) void d_swattn(const float* __restrict__ rq,
                                                const float* __restrict__ rk,
                                                const float* __restrict__ v,
                                                const float* __restrict__ gates,
                                                float* __restrict__ obuf) {
  int gid = blockIdx.x * 256 + threadIdx.x;  // 65536
  int nh = gid >> 9, t = gid & 511;
  int h = nh & 7, ball = nh >> 3;
  int b = t >> 5, qi = t & 31;
  const float* qp = rq + (size_t)gid * 32;
  float sc[64];
  float mx = -INFINITY;
#pragma unroll
  for (int kk = 0; kk < 64; ++kk) {
    bool valid = (kk > qi) && (kk <= qi + 32) && ((b > 0) || (kk >= 32));
    float s = -INFINITY;
    if (valid) {
      int tk = (kk < 32) ? ((b - 1) * 32 + kk) : (b * 32 + kk - 32);
      const float* kp = rk + ((size_t)nh * 512 + tk) * 32;
      s = 0.f;
      for (int d = 0; d < 32; ++d) s += qp[d] * kp[d];
      s *= SCALE_;
    }
    sc[kk] = s;
    mx = fmaxf(mx, s);
  }
  float den = 0.f;
  float num[32];
#pragma unroll
  for (int d = 0; d < 32; ++d) num[d] = 0.f;
#pragma unroll
  for (int kk = 0; kk < 64; ++kk) {
    bool valid = (kk > qi) && (kk <= qi + 32) && ((b > 0) || (kk >= 32));
    if (valid) {
      float p = expf(sc[kk] - mx);
      den += p;
      int tk = (kk < 32) ? ((b - 1) * 32 + kk) : (b * 32 + kk - 32);
      const float* vp = v + ((size_t)nh * 512 + tk) * 32;
      for (int d = 0; d < 32; ++d) num[d] += p * vp[d];
    }
  }
  float inv = 1.f / den;
  float g2 = gates[(size_t)(ball * 512 + t) * 24 + h * 3 + 2];
  float* op = obuf + (size_t)(ball * 512 + t) * 256 + h * 32;
  for (int d = 0; d < 32; ++d) op[d] += num[d] * inv * g2;
}

// final projection tiled: out = obuf @ Wo (f32 store)
__global__ __launch_bounds__(256) void k_out(const float* __restrict__ A,
                                             const float* __restrict__ B,
                                             float* __restrict__ C) {
  __shared__ float As[32][64];
  __shared__ float Bs[32][64];
  const int m0 = blockIdx.x * 64;
  const int n0 = blockIdx.y * 64;
  const int tid = threadIdx.x;
  const int tx = tid & 15, ty = tid >> 4;
  float acc[4][4] = {};
  for (int k0 = 0; k0 < 256; k0 += 32) {
#pragma unroll
    for (int i = 0; i < 8; ++i) {
      int li = tid + i * 256;
      int r = li >> 5, c = li & 31;
      As[c][r] = A[(size_t)(m0 + r) * 256 + k0 + c];
    }
#pragma unroll
    for (int i = 0; i < 8; ++i) {
      int li = tid + i * 256;
      int r = li >> 6, c = li & 63;
      Bs[r][c] = B[(size_t)(k0 + r) * 256 + n0 + c];
    }
    __syncthreads();
#pragma unroll
    for (int kk = 0; kk < 32; ++kk) {
      float a[4], b[4];
#pragma unroll
      for (int i = 0; i < 4; ++i) a[i] = As[kk][ty * 4 + i];
#pragma unroll
      for (int j = 0; j < 4; ++j) b[j] = Bs[kk][tx * 4 + j];
#pragma unroll
      for (int i = 0; i < 4; ++i)
#pragma unroll
        for (int j = 0; j < 4; ++j) acc[i][j] += a[i] * b[j];
    }
    __syncthreads();
  }
#pragma unroll
  for (int i = 0; i < 4; ++i) {
    int row = m0 + ty * 4 + i;
#pragma unroll
    for (int j = 0; j < 4; ++j)
      C[(size_t)row * 256 + n0 + tx * 4 + j] = acc[i][j];
  }
}

extern "C" void kernel_launch(void* const* d_in, const int* in_sizes, int n_in,
                              void* d_out, int out_size, void* d_ws, size_t ws_size,
                              hipStream_t stream) {
  const float* x      = (const float*)d_in[0];
  const float* pos    = (const float*)d_in[1];
  const float* Wpe    = (const float*)d_in[2];
  const float* bpe    = (const float*)d_in[3];
  const float* rms_w  = (const float*)d_in[4];
  const float* Wqkv   = (const float*)d_in[5];
  const float* kpos   = (const float*)d_in[6];
  const float* vpos   = (const float*)d_in[7];
  const float* kw1    = (const float*)d_in[8];
  const float* kw2    = (const float*)d_in[9];
  const float* vw1    = (const float*)d_in[10];
  const float* vw2    = (const float*)d_in[11];
  const float* mem_ck = (const float*)d_in[12];
  const float* mem_cv = (const float*)d_in[13];
  const float* Wg     = (const float*)d_in[14];
  const float* Wo     = (const float*)d_in[15];
  float* out = (float*)d_out;

  float* ws = (float*)d_ws;
  const size_t TOK = 2097152;  // 8192*256
  float* hn    = ws;
  float* q     = ws + TOK;
  float* k     = ws + 2 * TOK;
  float* v     = ws + 3 * TOK;
  float* rq    = ws + 4 * TOK;
  float* rk    = ws + 5 * TOK;
  float* obuf  = ws + 6 * TOK;
  float* hh    = ws + 7 * TOK;       // 4,063,232
  float* ck    = hh + 4063232;
  float* cv    = ck + 126976;
  float* gates = cv + 126976;
  float* rope  = gates + 196608;
  float* pm    = rope + 16384;
  int*   sel   = (int*)(pm + 64);

  d_rope<<<32, 256, 0, stream>>>(rope);
  d_pm<<<1, 64, 0, stream>>>(pos, pm);
  d_hn<<<32, 256, 0, stream>>>(x, pos, pm, Wpe, bpe, rms_w, hn);
  k_qkv<<<dim3(128, 12), 256, 0, stream>>>(hn, Wqkv, q, k, v);
  d_rot<<<4096, 256, 0, stream>>>(q, rope, rq);
  d_rot<<<4096, 256, 0, stream>>>(k, rope, rk);
  d_gates<<<768, 256, 0, stream>>>(hn, Wg, gates);
  k_gmlp1<<<dim3(8, 16, 8), 256, 0, stream>>>(k, kpos, kw1, hh);
  d_g2<<<496, 256, 0, stream>>>(hh, kw2, ck);
  k_gmlp1<<<dim3(8, 16, 8), 256, 0, stream>>>(v, vpos, vw1, hh);
  d_g2<<<496, 256, 0, stream>>>(hh, vw2, cv);
  d_cattn<<<256, 256, 0, stream>>>(q, ck, cv, mem_ck, mem_cv, gates, obuf, sel);
  d_fattn<<<256, 256, 0, stream>>>(rq, rk, v, sel, gates, obuf);
  d_swattn<<<256, 256, 0, stream>>>(rq, rk, v, gates, obuf);
  k_out<<<dim3(128, 4), 256, 0, stream>>>(obuf, Wo, out);
}

// Round 9
// 770.362 us; speedup vs baseline: 4.4614x; 1.1996x over previous
//
#include <hip/hip_runtime.h>
#include <hip/hip_bf16.h>
#include <math.h>

#define SCALE_ 0.17677669529663687f

// rope[t][j] = (cos, sin) of t * 10000^(-j/16), computed in double.
__global__ __launch_bounds__(256) void d_rope(float* __restrict__ rope) {
  int i = blockIdx.x * 256 + threadIdx.x;  // 8192 = 512*16
  int t = i >> 4, j = i & 15;
  double inv = pow(10000.0, -(double)j / 16.0);
  double ang = (double)t * inv;
  rope[2 * i]     = (float)cos(ang);
  rope[2 * i + 1] = (float)sin(ang);
}

// pm[ball][c] = mean over 512 tokens of pos
__global__ __launch_bounds__(64) void d_pm(const float* __restrict__ pos,
                                           float* __restrict__ pm) {
  int i = threadIdx.x;
  if (i >= 48) return;
  int ball = i / 3, c = i % 3;
  float s = 0.f;
  for (int t = 0; t < 512; ++t) s += pos[(size_t)(ball * 512 + t) * 3 + c];
  pm[i] = s * (1.f / 512.f);
}

// hn[tok][d] = RMSNorm(x + rel@Wpe + bpe) * rms_w  (one thread per token; exact
// sequential sum order — do NOT tree-reduce: sel argmax is ulp-sensitive)
__global__ __launch_bounds__(256) void d_hn(const float* __restrict__ x,
                                            const float* __restrict__ pos,
                                            const float* __restrict__ pm,
                                            const float* __restrict__ Wpe,
                                            const float* __restrict__ bpe,
                                            const float* __restrict__ rmsw,
                                            float* __restrict__ hn) {
  int tok = blockIdx.x * 256 + threadIdx.x;  // 8192
  int ball = tok >> 9;
  float r0 = pos[tok * 3 + 0] - pm[ball * 3 + 0];
  float r1 = pos[tok * 3 + 1] - pm[ball * 3 + 1];
  float r2 = pos[tok * 3 + 2] - pm[ball * 3 + 2];
  const float* xr = x + (size_t)tok * 256;
  float ss = 0.f;
  for (int d = 0; d < 256; ++d) {
    float hx = xr[d] + r0 * Wpe[d] + r1 * Wpe[256 + d] + r2 * Wpe[512 + d] + bpe[d];
    ss += hx * hx;
  }
  float inv = 1.f / sqrtf(ss * (1.f / 256.f) + 1e-6f);
  float* hr = hn + (size_t)tok * 256;
  for (int d = 0; d < 256; ++d) {
    float hx = xr[d] + r0 * Wpe[d] + r1 * Wpe[256 + d] + r2 * Wpe[512 + d] + bpe[d];
    hr[d] = hx * inv * rmsw[d];
  }
}

// qkv = hn @ Wqkv, tiled 64x64 (padded As), scatter q/k/v head-major
__global__ __launch_bounds__(256) void k_qkv(const float* __restrict__ A,
                                             const float* __restrict__ B,
                                             float* __restrict__ qo,
                                             float* __restrict__ ko,
                                             float* __restrict__ vo) {
  __shared__ float As[32][65];
  __shared__ float Bs[32][64];
  const int m0 = blockIdx.x * 64;
  const int n0 = blockIdx.y * 64;
  const int tid = threadIdx.x;
  const int tx = tid & 15, ty = tid >> 4;
  float acc[4][4] = {};
  for (int k0 = 0; k0 < 256; k0 += 32) {
#pragma unroll
    for (int i = 0; i < 8; ++i) {
      int li = tid + i * 256;
      int r = li >> 5, c = li & 31;
      As[c][r] = A[(size_t)(m0 + r) * 256 + k0 + c];
    }
#pragma unroll
    for (int i = 0; i < 8; ++i) {
      int li = tid + i * 256;
      int r = li >> 6, c = li & 63;
      Bs[r][c] = B[(size_t)(k0 + r) * 768 + n0 + c];
    }
    __syncthreads();
#pragma unroll
    for (int kk = 0; kk < 32; ++kk) {
      float a[4], b[4];
#pragma unroll
      for (int i = 0; i < 4; ++i) a[i] = As[kk][ty * 4 + i];
#pragma unroll
      for (int j = 0; j < 4; ++j) b[j] = Bs[kk][tx * 4 + j];
#pragma unroll
      for (int i = 0; i < 4; ++i)
#pragma unroll
        for (int j = 0; j < 4; ++j) acc[i][j] += a[i] * b[j];
    }
    __syncthreads();
  }
#pragma unroll
  for (int i = 0; i < 4; ++i) {
    int row = m0 + ty * 4 + i;
    int nb = row >> 9, t = row & 511;
#pragma unroll
    for (int j = 0; j < 4; ++j) {
      int col = n0 + tx * 4 + j;
      int which = col >> 8, cj = col & 255;
      int h = cj >> 5, d = cj & 31;
      float* dst = which == 0 ? qo : which == 1 ? ko : vo;
      dst[((size_t)(nb * 8 + h) * 512 + t) * 32 + d] = acc[i][j];
    }
  }
}

// rotate: dst = rope(src), one thread per (nh, t, pair)
__global__ __launch_bounds__(256) void d_rot(const float* __restrict__ src,
                                             const float* __restrict__ rope,
                                             float* __restrict__ dst) {
  int gid = blockIdx.x * 256 + threadIdx.x;  // 1,048,576
  int p = gid & 15;
  int t = (gid >> 4) & 511;
  int nh = gid >> 13;
  float c = rope[(t * 16 + p) * 2], s = rope[(t * 16 + p) * 2 + 1];
  const float* sp = src + ((size_t)nh * 512 + t) * 32;
  float x1 = sp[2 * p], x2 = sp[2 * p + 1];
  float* dp = dst + ((size_t)nh * 512 + t) * 32;
  dp[2 * p]     = x1 * c - x2 * s;
  dp[2 * p + 1] = x1 * s + x2 * c;
}

// gates = sigmoid(hn @ Wg), one thread per (token, j)
__global__ __launch_bounds__(256) void d_gates(const float* __restrict__ hn,
                                               const float* __restrict__ Wg,
                                               float* __restrict__ gates) {
  int gid = blockIdx.x * 256 + threadIdx.x;  // 196608
  int tok = gid / 24, j = gid % 24;
  const float* hr = hn + (size_t)tok * 256;
  float s = 0.f;
  for (int d = 0; d < 256; ++d) s += hr[d] * Wg[d * 24 + j];
  gates[gid] = 1.f / (1.f + expf(-s));
}

// gMLP layer 1 tiled (padded As): hh[h][row][o] = relu((gather(kv)+posw) @ w1[h])
__global__ __launch_bounds__(256) void k_gmlp1(const float* __restrict__ kv,
                                               const float* __restrict__ posw,
                                               const float* __restrict__ w1,
                                               float* __restrict__ hb) {
  __shared__ float As[32][65];
  __shared__ float Bs[32][64];
  const int h = blockIdx.z;
  const int m0 = blockIdx.x * 64;
  const int n0 = blockIdx.y * 64;
  const int tid = threadIdx.x;
  const int tx = tid & 15, ty = tid >> 4;
  float acc[4][4] = {};
  for (int k0 = 0; k0 < 1024; k0 += 32) {
#pragma unroll
    for (int i = 0; i < 8; ++i) {
      int li = tid + i * 256;
      int r = li >> 5, c = li & 31;
      int row = m0 + r;
      float vv = 0.f;
      if (row < 496) {
        int nb = row / 31, bb = row % 31;
        vv = kv[((size_t)(nb * 8 + h) * 512 + bb * 16) * 32 + k0 + c] + posw[h * 1024 + k0 + c];
      }
      As[c][r] = vv;
    }
#pragma unroll
    for (int i = 0; i < 8; ++i) {
      int li = tid + i * 256;
      int r = li >> 6, c = li & 63;
      Bs[r][c] = w1[(size_t)h * 1048576 + (size_t)(k0 + r) * 1024 + n0 + c];
    }
    __syncthreads();
#pragma unroll
    for (int kk = 0; kk < 32; ++kk) {
      float a[4], b[4];
#pragma unroll
      for (int i = 0; i < 4; ++i) a[i] = As[kk][ty * 4 + i];
#pragma unroll
      for (int j = 0; j < 4; ++j) b[j] = Bs[kk][tx * 4 + j];
#pragma unroll
      for (int i = 0; i < 4; ++i)
#pragma unroll
        for (int j = 0; j < 4; ++j) acc[i][j] += a[i] * b[j];
    }
    __syncthreads();
  }
#pragma unroll
  for (int i = 0; i < 4; ++i) {
    int row = m0 + ty * 4 + i;
    if (row < 496) {
#pragma unroll
      for (int j = 0; j < 4; ++j)
        hb[((size_t)h * 496 + row) * 1024 + n0 + tx * 4 + j] = fmaxf(acc[i][j], 0.f);
    }
  }
}

// gMLP out: one thread per output, exact sequential i order (sel-sensitive)
__global__ __launch_bounds__(256) void d_g2(const float* __restrict__ hh,
                                            const float* __restrict__ w2,
                                            float* __restrict__ outp) {
  int gid = blockIdx.x * 256 + threadIdx.x;  // 126976
  int o = gid & 31;
  int rem = gid >> 5;                  // h*496 + row
  int h = rem / 496, row = rem % 496;
  int nb = row / 31, bb = row % 31;
  const float* hr = hh + (size_t)rem * 1024;
  const float* w2p = w2 + (size_t)h * 32768 + o;
  float s = 0.f;
  for (int i = 0; i < 1024; ++i) s += hr[i] * w2p[(size_t)i * 32];
  outp[((size_t)(nb * 8 + h) * 31 + bb) * 32 + o] = s;
}

// compressed attention, one thread per (nh, t): writes obuf = g0*c_out, emits sel
__global__ __launch_bounds__(256) void d_cattn(const float* __restrict__ q,
                                               const float* __restrict__ ck,
                                               const float* __restrict__ cv,
                                               const float* __restrict__ mem_ck,
                                               const float* __restrict__ mem_cv,
                                               const float* __restrict__ gates,
                                               float* __restrict__ obuf,
                                               int* __restrict__ sel) {
  int gid = blockIdx.x * 256 + threadIdx.x;  // 65536
  int nh = gid >> 9, t = gid & 511;
  int h = nh & 7, ball = nh >> 3;
  const float* qp = q + (size_t)gid * 32;
  float sc[32];
  float mx = -INFINITY;
#pragma unroll
  for (int j = 0; j < 32; ++j) {
    float s = -INFINITY;
    bool valid = (j == 0) || (t >= (j - 1) * 16 + 31);
    if (valid) {
      const float* kp = (j == 0) ? (mem_ck + h * 32)
                                 : (ck + ((size_t)nh * 31 + (j - 1)) * 32);
      s = 0.f;
      for (int d = 0; d < 32; ++d) s += qp[d] * kp[d];
      s *= SCALE_;
    }
    sc[j] = s;
    mx = fmaxf(mx, s);
  }
  float e[32];
  float den = 0.f;
#pragma unroll
  for (int j = 0; j < 32; ++j) { e[j] = expf(sc[j] - mx); den += e[j]; }
  float num[32];
#pragma unroll
  for (int d = 0; d < 32; ++d) num[d] = 0.f;
#pragma unroll
  for (int j = 0; j < 32; ++j) {
    const float* vp = (j == 0) ? (mem_cv + h * 32)
                               : (cv + ((size_t)nh * 31 + (j - 1)) * 32);
    float p = e[j];
    for (int d = 0; d < 32; ++d) num[d] += p * vp[d];
  }
  float inv = 1.f / den;
  float g0 = gates[(size_t)(ball * 512 + t) * 24 + h * 3];
  float* op = obuf + (size_t)(ball * 512 + t) * 256 + h * 32;
  for (int d = 0; d < 32; ++d) op[d] = num[d] * inv * g0;

  int s_idx = 0;
  if (t >= 32) {
    int fn = t >> 5;
    float best = -INFINITY;
    for (int f = 0; f < fn; ++f) {
      float im = 0.f;
#pragma unroll
      for (int j = 0; j < 31; ++j) {
        int a = j * 16, b2 = a + 32, fa = f * 32, fb = fa + 32;
        int lo = a > fa ? a : fa;
        int hi = b2 < fb ? b2 : fb;
        if (hi > lo) im += e[j + 1] * (float)(hi - lo) * (1.f / 32.f);
      }
      if (im > best) { best = im; s_idx = f; }
    }
  }
  sel[gid] = s_idx;
}

// fine attention, one thread per (nh, t): obuf += g1 * f_out
__global__ __launch_bounds__(256) void d_fattn(const float* __restrict__ rq,
                                               const float* __restrict__ rk,
                                               const float* __restrict__ v,
                                               const int* __restrict__ sel,
                                               const float* __restrict__ gates,
                                               float* __restrict__ obuf) {
  int gid = blockIdx.x * 256 + threadIdx.x;  // 65536
  int nh = gid >> 9, t = gid & 511;
  int h = nh & 7, ball = nh >> 3;
  int f0 = t >> 5, qi = t & 31;
  int sb = sel[gid];
  bool hs = (t >= 32);
  const float* qp = rq + (size_t)gid * 32;
  float so[32], ss[32];
  float mx = -INFINITY;
#pragma unroll
  for (int j = 0; j < 32; ++j) {
    float s = -INFINITY;
    if (qi >= j) {
      const float* kp = rk + ((size_t)nh * 512 + f0 * 32 + j) * 32;
      s = 0.f;
      for (int d = 0; d < 32; ++d) s += qp[d] * kp[d];
      s *= SCALE_;
    }
    so[j] = s;
    mx = fmaxf(mx, s);
  }
#pragma unroll
  for (int j = 0; j < 32; ++j) {
    float s = -INFINITY;
    if (hs) {
      const float* kp = rk + ((size_t)nh * 512 + sb * 32 + j) * 32;
      s = 0.f;
      for (int d = 0; d < 32; ++d) s += qp[d] * kp[d];
      s *= SCALE_;
    }
    ss[j] = s;
    mx = fmaxf(mx, s);
  }
  float den = 0.f;
  float num[32];
#pragma unroll
  for (int d = 0; d < 32; ++d) num[d] = 0.f;
#pragma unroll
  for (int j = 0; j < 32; ++j) {
    float p = expf(so[j] - mx);
    den += p;
    const float* vp = v + ((size_t)nh * 512 + f0 * 32 + j) * 32;
    for (int d = 0; d < 32; ++d) num[d] += p * vp[d];
  }
#pragma unroll
  for (int j = 0; j < 32; ++j) {
    float p = expf(ss[j] - mx);
    den += p;
    const float* vp = v + ((size_t)nh * 512 + sb * 32 + j) * 32;
    for (int d = 0; d < 32; ++d) num[d] += p * vp[d];
  }
  float inv = 1.f / den;
  float g1 = gates[(size_t)(ball * 512 + t) * 24 + h * 3 + 1];
  float* op = obuf + (size_t)(ball * 512 + t) * 256 + h * 32;
  for (int d = 0; d < 32; ++d) op[d] += num[d] * inv * g1;
}

// sliding-window attention, one thread per (nh, t): obuf += g2 * sw_out
__global__ __launch_bounds__(256) void d_swattn(const float* __restrict__ rq,
                                                const float* __restrict__ rk,
                                                const float* __restrict__ v,
                                                const float* __restrict__ gates,
                                                float* __restrict__ obuf) {
  int gid = blockIdx.x * 256 + threadIdx.x;  // 65536
  int nh = gid >> 9, t = gid & 511;
  int h = nh & 7, ball = nh >> 3;
  int b = t >> 5, qi = t & 31;
  const float* qp = rq + (size_t)gid * 32;
  float sc[64];
  float mx = -INFINITY;
#pragma unroll
  for (int kk = 0; kk < 64; ++kk) {
    bool valid = (kk > qi) && (kk <= qi + 32) && ((b > 0) || (kk >= 32));
    float s = -INFINITY;
    if (valid) {
      int tk = (kk < 32) ? ((b - 1) * 32 + kk) : (b * 32 + kk - 32);
      const float* kp = rk + ((size_t)nh * 512 + tk) * 32;
      s = 0.f;
      for (int d = 0; d < 32; ++d) s += qp[d] * kp[d];
      s *= SCALE_;
    }
    sc[kk] = s;
    mx = fmaxf(mx, s);
  }
  float den = 0.f;
  float num[32];
#pragma unroll
  for (int d = 0; d < 32; ++d) num[d] = 0.f;
#pragma unroll
  for (int kk = 0; kk < 64; ++kk) {
    bool valid = (kk > qi) && (kk <= qi + 32) && ((b > 0) || (kk >= 32));
    if (valid) {
      float p = expf(sc[kk] - mx);
      den += p;
      int tk = (kk < 32) ? ((b - 1) * 32 + kk) : (b * 32 + kk - 32);
      const float* vp = v + ((size_t)nh * 512 + tk) * 32;
      for (int d = 0; d < 32; ++d) num[d] += p * vp[d];
    }
  }
  float inv = 1.f / den;
  float g2 = gates[(size_t)(ball * 512 + t) * 24 + h * 3 + 2];
  float* op = obuf + (size_t)(ball * 512 + t) * 256 + h * 32;
  for (int d = 0; d < 32; ++d) op[d] += num[d] * inv * g2;
}

// final projection tiled (padded As): out = obuf @ Wo (f32 store)
__global__ __launch_bounds__(256) void k_out(const float* __restrict__ A,
                                             const float* __restrict__ B,
                                             float* __restrict__ C) {
  __shared__ float As[32][65];
  __shared__ float Bs[32][64];
  const int m0 = blockIdx.x * 64;
  const int n0 = blockIdx.y * 64;
  const int tid = threadIdx.x;
  const int tx = tid & 15, ty = tid >> 4;
  float acc[4][4] = {};
  for (int k0 = 0; k0 < 256; k0 += 32) {
#pragma unroll
    for (int i = 0; i < 8; ++i) {
      int li = tid + i * 256;
      int r = li >> 5, c = li & 31;
      As[c][r] = A[(size_t)(m0 + r) * 256 + k0 + c];
    }
#pragma unroll
    for (int i = 0; i < 8; ++i) {
      int li = tid + i * 256;
      int r = li >> 6, c = li & 63;
      Bs[r][c] = B[(size_t)(k0 + r) * 256 + n0 + c];
    }
    __syncthreads();
#pragma unroll
    for (int kk = 0; kk < 32; ++kk) {
      float a[4], b[4];
#pragma unroll
      for (int i = 0; i < 4; ++i) a[i] = As[kk][ty * 4 + i];
#pragma unroll
      for (int j = 0; j < 4; ++j) b[j] = Bs[kk][tx * 4 + j];
#pragma unroll
      for (int i = 0; i < 4; ++i)
#pragma unroll
        for (int j = 0; j < 4; ++j) acc[i][j] += a[i] * b[j];
    }
    __syncthreads();
  }
#pragma unroll
  for (int i = 0; i < 4; ++i) {
    int row = m0 + ty * 4 + i;
#pragma unroll
    for (int j = 0; j < 4; ++j)
      C[(size_t)row * 256 + n0 + tx * 4 + j] = acc[i][j];
  }
}

extern "C" void kernel_launch(void* const* d_in, const int* in_sizes, int n_in,
                              void* d_out, int out_size, void* d_ws, size_t ws_size,
                              hipStream_t stream) {
  const float* x      = (const float*)d_in[0];
  const float* pos    = (const float*)d_in[1];
  const float* Wpe    = (const float*)d_in[2];
  const float* bpe    = (const float*)d_in[3];
  const float* rms_w  = (const float*)d_in[4];
  const float* Wqkv   = (const float*)d_in[5];
  const float* kpos   = (const float*)d_in[6];
  const float* vpos   = (const float*)d_in[7];
  const float* kw1    = (const float*)d_in[8];
  const float* kw2    = (const float*)d_in[9];
  const float* vw1    = (const float*)d_in[10];
  const float* vw2    = (const float*)d_in[11];
  const float* mem_ck = (const float*)d_in[12];
  const float* mem_cv = (const float*)d_in[13];
  const float* Wg     = (const float*)d_in[14];
  const float* Wo     = (const float*)d_in[15];
  float* out = (float*)d_out;

  float* ws = (float*)d_ws;
  const size_t TOK = 2097152;  // 8192*256
  float* hn    = ws;
  float* q     = ws + TOK;
  float* k     = ws + 2 * TOK;
  float* v     = ws + 3 * TOK;
  float* rq    = ws + 4 * TOK;
  float* rk    = ws + 5 * TOK;
  float* obuf  = ws + 6 * TOK;
  float* hh    = ws + 7 * TOK;       // 4,063,232
  float* ck    = hh + 4063232;
  float* cv    = ck + 126976;
  float* gates = cv + 126976;
  float* rope  = gates + 196608;
  float* pm    = rope + 16384;
  int*   sel   = (int*)(pm + 64);

  d_rope<<<32, 256, 0, stream>>>(rope);
  d_pm<<<1, 64, 0, stream>>>(pos, pm);
  d_hn<<<32, 256, 0, stream>>>(x, pos, pm, Wpe, bpe, rms_w, hn);
  k_qkv<<<dim3(128, 12), 256, 0, stream>>>(hn, Wqkv, q, k, v);
  d_rot<<<4096, 256, 0, stream>>>(q, rope, rq);
  d_rot<<<4096, 256, 0, stream>>>(k, rope, rk);
  d_gates<<<768, 256, 0, stream>>>(hn, Wg, gates);
  k_gmlp1<<<dim3(8, 16, 8), 256, 0, stream>>>(k, kpos, kw1, hh);
  d_g2<<<496, 256, 0, stream>>>(hh, kw2, ck);
  k_gmlp1<<<dim3(8, 16, 8), 256, 0, stream>>>(v, vpos, vw1, hh);
  d_g2<<<496, 256, 0, stream>>>(hh, vw2, cv);
  d_cattn<<<256, 256, 0, stream>>>(q, ck, cv, mem_ck, mem_cv, gates, obuf, sel);
  d_fattn<<<256, 256, 0, stream>>>(rq, rk, v, sel, gates, obuf);
  d_swattn<<<256, 256, 0, stream>>>(rq, rk, v, gates, obuf);
  k_out<<<dim3(128, 4), 256, 0, stream>>>(obuf, Wo, out);
}